// Round 8
// baseline (5327.395 us; speedup 1.0000x reference)
//
#include <hip/hip_runtime.h>
#include <hip/hip_bf16.h>

#define TSEQ  200
#define BATCH 256
#define INDIM 32
#define HID   512
#define GATES 2048

typedef __bf16 bf16x8 __attribute__((ext_vector_type(8)));
typedef float  f32x4  __attribute__((ext_vector_type(4)));
typedef unsigned long long u64;

// ---- workspace layout (bytes) ----
// Packed weights live at the front; after every block's one-time register
// preload (gated by a preload flag), PW_HH0/PW_IH1 become DEAD and the h
// rings are overlaid on top of them. Total footprint 0x6A6000 (~7.0 MB),
// below the round-5-proven 0x826000.
static constexpr size_t OFF_PW_IH0 = 0;          // 128 KB (preserved)
static constexpr size_t OFF_PW_HH0 = 0x20000;    // 2 MB   (overlaid by ring h1)
static constexpr size_t OFF_PW_IH1 = 0x220000;   // 2 MB   (partly overlaid by ring h2)
static constexpr size_t OFF_PW_HH1 = 0x420000;   // 2 MB   (preserved)
static constexpr size_t OFF_B0     = 0x620000;   // 8 KB
static constexpr size_t OFF_B1     = 0x622000;   // 8 KB
// h rings, TAGGED 8-byte granules: frag (8 bf16 per lane) -> 3 u64 granules
// [e0|e1|e2|tag][e3|e4|e5|tag][e6|e7|--|tag]; u64 stores/loads are naturally
// aligned 8B => single-copy atomic => tag validity implies payload validity.
static constexpr size_t SLOT_SZ    = 0x60000;    // 16384 frag-lanes * 24 B
static constexpr size_t OFF_RH1    = 0x20000;    // 4 slots -> ends 0x1A0000
static constexpr size_t OFF_RH2    = 0x1A0000;   // 4 slots -> ends 0x320000
static constexpr size_t OFF_CTR    = 0x624000;   // per-group progress-flag lines
static constexpr size_t OFF_H2P    = 0x626000;   // 512 KB fp32 (final h2)
static constexpr size_t ZERO_OFF   = OFF_CTR;    // rings are NOT memset (see tags)
static constexpr size_t ZERO_LEN   = OFF_H2P + 0x80000 - OFF_CTR;

__device__ __forceinline__ float sigm(float v) { return 1.f / (1.f + __expf(-v)); }

// guarded fast tanh: e = exp(-2|v|) in (0,1]; tanh(|v|) = (1-e)/(1+e); restore sign.
__device__ __forceinline__ float tanh_fast(float v) {
    float e = __expf(-2.0f * fabsf(v));
    float t = (1.0f - e) / (1.0f + e);
    return copysignf(t, v);
}

__device__ __forceinline__ bf16x8 as_bf16x8(f32x4 v) {
    union { f32x4 f; bf16x8 b; } u; u.f = v; return u.b;
}

// 8B tagged-granule ops: relaxed agent-scope atomics = plain dwordx2 with
// MALL-coherent policy, compiler-tracked (no manual waitcnt hazards),
// coalesced like ordinary vector loads.
__device__ __forceinline__ u64 ld_gran(const void* p) {
    return __hip_atomic_load((const u64*)p, __ATOMIC_RELAXED, __HIP_MEMORY_SCOPE_AGENT);
}
__device__ __forceinline__ void st_gran(void* p, u64 v) {
    __hip_atomic_store((u64*)p, v, __ATOMIC_RELAXED, __HIP_MEMORY_SCOPE_AGENT);
}

// Untracked coherent flag load (issued early; consume only after a manual
// s_waitcnt vmcnt(0) + sched_barrier(0) -- guide rule #18).
__device__ __forceinline__ unsigned load_flag_async(const unsigned* p) {
    unsigned v;
    asm volatile("global_load_dword %0, %1, off sc0 sc1"
                 : "=v"(v) : "v"(p) : "memory");
    return v;
}
// Self-fencing coherent flag load (rare retry paths).
__device__ __forceinline__ unsigned load_flag_coh(const unsigned* p) {
    unsigned v;
    asm volatile("global_load_dword %0, %1, off sc0 sc1\n\t"
                 "s_waitcnt vmcnt(0)"
                 : "=v"(v) : "v"(p) : "memory");
    return v;
}

// Pack weight matrix W[2048][K] (fp32, row-major) into MFMA B-fragment order (bf16).
__global__ void pack_w(const float* __restrict__ W, __bf16* __restrict__ out, int ktlog2)
{
    int tid = blockIdx.x * 256 + threadIdx.x;
    int K = 32 << ktlog2;
    int j    = tid & 7;
    int lane = (tid >> 3) & 63;
    int rest = tid >> 9;
    int kt   = rest & ((1 << ktlog2) - 1);
    int r2   = rest >> ktlog2;
    int lnt  = r2 & 7;
    int bn   = r2 >> 3;
    int type = lnt >> 1, half = lnt & 1;
    int g    = type * 512 + bn * 32 + half * 16 + (lane & 15);
    int kcol = kt * 32 + (lane >> 4) * 8 + j;
    out[tid] = (__bf16)W[g * K + kcol];
}

__global__ void bias_comb(const float* __restrict__ a0, const float* __restrict__ a1,
                          const float* __restrict__ a2, const float* __restrict__ a3,
                          float* __restrict__ o0, float* __restrict__ o1)
{
    int tid = blockIdx.x * 256 + threadIdx.x;
    if (tid < GATES) { o0[tid] = a0[tid] + a1[tid]; o1[tid] = a2[tid] + a3[tid]; }
}

// Persistent pipelined 2-layer LSTM, weights register-resident.
// Grid: 256 blocks x 256 threads. Blocks 0..127 layer0, 128..255 layer1.
// Protocol v4: TAG-IN-DATA at 8-byte (atomic) granularity.
//  - producers fire tagged granule stores: no store-ack, no flag, no barrier
//    on the critical path. Consumers load granules and retry stale ones.
//  - tags: h1[t] -> t+1; h2[t] -> t+1 (u16, <= 201; never 0..4-collision with
//    weight garbage because those bit patterns are ~1e-41 denormals).
//  - every ring slot is written (round s) before its first tagged read
//    (round s+1), so rings need no initialization; zero-state rounds
//    (k=0 layer0 recurrent, k=1 layer1 h2) skip ring reads entirely.
//  - overwrite safety: progress flags (flag=1 after weight preload with a
//    vmcnt drain; flag=k+2 after staging round k). Writer at round k requires
//    all 32 flags >= max(1, k-1) -- checked off the critical path from a
//    flag line loaded asynchronously at round start.
__global__ __launch_bounds__(256, 1) void lstm_persist(const float* __restrict__ x,
                                                       const float* __restrict__ wfc,
                                                       const float* __restrict__ bfc,
                                                       char* __restrict__ ws,
                                                       float* __restrict__ out)
{
    const int layer = blockIdx.x >> 7;
    const int lb    = blockIdx.x & 127;
    const int mtp   = lb >> 4;            // batch group: [mtp*32, +32)
    const int bn    = lb & 15;            // hidden tile: [bn*32, +32)
    const int wid   = threadIdx.x >> 6;
    const int half  = wid & 1;
    const int kh    = wid >> 1;
    const int lane  = threadIdx.x & 63;
    const int q     = lane >> 4;
    const int c16   = lane & 15;
    unsigned* flg   = (unsigned*)(ws + OFF_CTR) + (size_t)mtp * 64;  // 32 flags, 1 line

    __shared__ float  red[2][64][33];     // padded: conflict-free cross-wave reduction
    __shared__ __bf16 htr[1024];          // h transpose staging (kh0 waves only)
    __shared__ bf16x8 stg[2][2][16][64];  // A-frag staging [kh][half][kt][lane], 64 KB

    const float* bias = (const float*)(ws + (layer ? OFF_B1 : OFF_B0));
    const int hidx = bn * 32 + half * 16 + c16;     // C/D col = lane&15
    const float bi  = bias[hidx];
    const float bff = bias[512 + hidx];
    const float bg  = bias[1024 + hidx];
    const float bo  = bias[1536 + hidx];

    const bf16x8* __restrict__ pBx = (const bf16x8*)(ws + OFF_PW_IH0);
    const bf16x8* __restrict__ pBh = (const bf16x8*)(ws + OFF_PW_HH0);
    const bf16x8* __restrict__ pB1 = (const bf16x8*)(ws + OFF_PW_IH1);
    const bf16x8* __restrict__ pB2 = (const bf16x8*)(ws + OFF_PW_HH1);
    float* __restrict__ h2p = (float*)(ws + OFF_H2P);

    // ---- preload weight slice into registers (plain cached loads) ----
    f32x4 Bw[64];                         // layer1: [kt(16)][ty(4)]; layer0: [kt(8)][ty(4)]
    f32x4 Bx[4];                          // layer0 x-projection frags
    if (layer == 0) {
        #pragma unroll
        for (int j = 0; j < 8; ++j)
            #pragma unroll
            for (int ty = 0; ty < 4; ++ty)
                Bw[j * 4 + ty] = *(const f32x4*)&pBh[((bn * 8 + ty * 2 + half) * 16 + kh * 8 + j) * 64 + lane];
        #pragma unroll
        for (int ty = 0; ty < 4; ++ty)
            Bx[ty] = *(const f32x4*)&pBx[(bn * 8 + ty * 2 + half) * 64 + lane];
    } else {
        const bf16x8* __restrict__ pW = kh ? pB2 : pB1;
        #pragma unroll
        for (int j = 0; j < 16; ++j)
            #pragma unroll
            for (int ty = 0; ty < 4; ++ty)
                Bw[j * 4 + ty] = *(const f32x4*)&pW[((bn * 8 + ty * 2 + half) * 16 + j) * 64 + lane];
    }
    // drain weight loads, then post the preload flag (=1): peers may overwrite
    // the PW region (rings) only after ALL blocks posted this.
    asm volatile("s_waitcnt vmcnt(0)" ::: "memory");
    __builtin_amdgcn_sched_barrier(0);
    __syncthreads();
    if (threadIdx.x == 0)
        __hip_atomic_store(flg + layer * 16 + bn, 1u, __ATOMIC_RELAXED,
                           __HIP_MEMORY_SCOPE_AGENT);

    float creg[8] = {0.f,0.f,0.f,0.f,0.f,0.f,0.f,0.f};   // c state (kh0 waves)

    // Load NF tagged frags (3 granules each) from slot base sb, retry until all
    // tags == want, then stage payloads to stg[kh][half][0..NF).
    auto stage_frags = [&](const char* sb, int kt0, int NF, int want) {
        const int abase = (mtp * 2 + half) * 16 + kt0;
        const u64 w = (u64)(unsigned)want;
        u64 g0[16], g1[16], g2[16];
        #pragma unroll
        for (int j = 0; j < 16; ++j) if (j < NF) {
            const char* p = sb + ((size_t)(abase + j) * 64 + lane) * 24;
            g0[j] = ld_gran(p); g1[j] = ld_gran(p + 8); g2[j] = ld_gran(p + 16);
        }
        while (true) {
            bool ok = true;
            #pragma unroll
            for (int j = 0; j < 16; ++j) if (j < NF)
                ok &= ((g0[j] >> 48) == w) & ((g1[j] >> 48) == w) & ((g2[j] >> 48) == w);
            if (__all(ok)) break;
            __builtin_amdgcn_s_sleep(1);
            #pragma unroll
            for (int j = 0; j < 16; ++j) if (j < NF) {
                const char* p = sb + ((size_t)(abase + j) * 64 + lane) * 24;
                if ((g0[j] >> 48) != w) g0[j] = ld_gran(p);
                if ((g1[j] >> 48) != w) g1[j] = ld_gran(p + 8);
                if ((g2[j] >> 48) != w) g2[j] = ld_gran(p + 16);
            }
        }
        #pragma unroll
        for (int j = 0; j < 16; ++j) if (j < NF) {
            union { unsigned short s[8]; bf16x8 b; } cv;
            cv.s[0] = (unsigned short)g0[j];
            cv.s[1] = (unsigned short)(g0[j] >> 16);
            cv.s[2] = (unsigned short)(g0[j] >> 32);
            cv.s[3] = (unsigned short)g1[j];
            cv.s[4] = (unsigned short)(g1[j] >> 16);
            cv.s[5] = (unsigned short)(g1[j] >> 32);
            cv.s[6] = (unsigned short)g2[j];
            cv.s[7] = (unsigned short)(g2[j] >> 16);
            stg[kh][half][j][lane] = cv.b;
        }
    };

    for (int k = 0; k <= TSEQ; ++k) {
        const bool active = layer ? (k >= 1) : (k < TSEQ);
        if (active) {
            const int t = k - layer;
            f32x4 acc[2][4] = {};
            const bool recur = (layer == 1) || (k > 0);   // L0 k=0: h1[-1]=0
            const bool h2ok  = (layer == 0) || (k > 1);   // L1 k=1: h2[-1]=0

            const char* rd_h1 = ws + OFF_RH1 + (size_t)((k + 3) & 3) * SLOT_SZ; // h1[k-1], tag k
            const char* rd_h2 = ws + OFF_RH2 + (size_t)((k + 2) & 3) * SLOT_SZ; // h2[k-2], tag k-1

            // phase 1: issue overwrite-guard flag read (kh0), stage ring inputs
            unsigned pf = 0;
            if (kh == 0 && lane < 32) pf = load_flag_async(flg + lane);

            if (layer == 0) {
                if (recur) stage_frags(rd_h1, kh * 8, 8, k);
            } else {
                if (kh == 0) stage_frags(rd_h1, 0, 16, k);
                else if (h2ok) stage_frags(rd_h2, 0, 16, k - 1);
            }

            bf16x8 ax[2];
            if (layer == 0 && kh == 0) {
                #pragma unroll
                for (int m = 0; m < 2; ++m) {
                    const int b = (mtp * 2 + m) * 16 + c16;
                    const float* xp = x + ((size_t)b * TSEQ + t) * INDIM + q * 8;
                    float4 xlo = *(const float4*)xp;
                    float4 xhi = *(const float4*)(xp + 4);
                    ax[m][0] = (__bf16)xlo.x; ax[m][1] = (__bf16)xlo.y;
                    ax[m][2] = (__bf16)xlo.z; ax[m][3] = (__bf16)xlo.w;
                    ax[m][4] = (__bf16)xhi.x; ax[m][5] = (__bf16)xhi.y;
                    ax[m][6] = (__bf16)xhi.z; ax[m][7] = (__bf16)xhi.w;
                }
            }

            __syncthreads();                                 // S1: staging complete
            if (threadIdx.x == 0)                            // prog: staged round k
                __hip_atomic_store(flg + layer * 16 + bn, (unsigned)(k + 2),
                                   __ATOMIC_RELAXED, __HIP_MEMORY_SCOPE_AGENT);

            // phase 2: LDS -> registers
            bf16x8 a0[16], a1[16];
            if (layer == 0) {
                if (recur) {
                    #pragma unroll
                    for (int j = 0; j < 8; ++j) {
                        a0[j]     = stg[kh][0][j][lane];
                        a0[8 + j] = stg[kh][1][j][lane];
                    }
                }
            } else if (kh == 0 || h2ok) {
                #pragma unroll
                for (int j = 0; j < 8; ++j) {
                    a0[j]     = stg[kh][0][j][lane];
                    a0[8 + j] = stg[kh][1][j][lane];
                    a1[j]     = stg[kh][0][8 + j][lane];
                    a1[8 + j] = stg[kh][1][8 + j][lane];
                }
            }
            __syncthreads();                                 // S_read: stg reuse guard

            // phase 3: MFMAs
            if (layer == 0) {
                if (kh == 0) {
                    #pragma unroll
                    for (int m = 0; m < 2; ++m)
                        #pragma unroll
                        for (int ty = 0; ty < 4; ++ty)
                            acc[m][ty] = __builtin_amdgcn_mfma_f32_16x16x32_bf16(ax[m], as_bf16x8(Bx[ty]), acc[m][ty], 0, 0, 0);
                }
                if (recur) {
                    #pragma unroll
                    for (int j = 0; j < 8; ++j) {
                        #pragma unroll
                        for (int ty = 0; ty < 4; ++ty) {
                            acc[0][ty] = __builtin_amdgcn_mfma_f32_16x16x32_bf16(a0[j],     as_bf16x8(Bw[j * 4 + ty]), acc[0][ty], 0, 0, 0);
                            acc[1][ty] = __builtin_amdgcn_mfma_f32_16x16x32_bf16(a0[8 + j], as_bf16x8(Bw[j * 4 + ty]), acc[1][ty], 0, 0, 0);
                        }
                    }
                }
            } else if (kh == 0 || h2ok) {
                #pragma unroll
                for (int j = 0; j < 8; ++j) {
                    #pragma unroll
                    for (int ty = 0; ty < 4; ++ty) {
                        acc[0][ty] = __builtin_amdgcn_mfma_f32_16x16x32_bf16(a0[j],     as_bf16x8(Bw[j * 4 + ty]), acc[0][ty], 0, 0, 0);
                        acc[1][ty] = __builtin_amdgcn_mfma_f32_16x16x32_bf16(a0[8 + j], as_bf16x8(Bw[j * 4 + ty]), acc[1][ty], 0, 0, 0);
                    }
                }
                #pragma unroll
                for (int j = 0; j < 8; ++j) {
                    #pragma unroll
                    for (int ty = 0; ty < 4; ++ty) {
                        acc[0][ty] = __builtin_amdgcn_mfma_f32_16x16x32_bf16(a1[j],     as_bf16x8(Bw[(8 + j) * 4 + ty]), acc[0][ty], 0, 0, 0);
                        acc[1][ty] = __builtin_amdgcn_mfma_f32_16x16x32_bf16(a1[8 + j], as_bf16x8(Bw[(8 + j) * 4 + ty]), acc[1][ty], 0, 0, 0);
                    }
                }
            }

            // phase 4: cross-wave K reduction
            if (kh == 1) {
                #pragma unroll
                for (int m = 0; m < 2; ++m)
                    #pragma unroll
                    for (int ty = 0; ty < 4; ++ty)
                        #pragma unroll
                        for (int r = 0; r < 4; ++r)
                            red[half][lane][m * 16 + ty * 4 + r] = acc[m][ty][r];
            }
            __syncthreads();                                 // S2: reduction ready

            if (kh == 0) {
                #pragma unroll
                for (int m = 0; m < 2; ++m) {
                    #pragma unroll
                    for (int r = 0; r < 4; ++r) {
                        float pi  = acc[m][0][r] + red[half][lane][m * 16 + r]      + bi;
                        float pff = acc[m][1][r] + red[half][lane][m * 16 + 4 + r]  + bff;
                        float pg  = acc[m][2][r] + red[half][lane][m * 16 + 8 + r]  + bg;
                        float po  = acc[m][3][r] + red[half][lane][m * 16 + 12 + r] + bo;
                        float cn = sigm(pff) * creg[m * 4 + r] + sigm(pi) * tanh_fast(pg);
                        float hn = sigm(po) * tanh_fast(cn);
                        creg[m * 4 + r] = cn;
                        htr[half * 512 + (m * 16 + q * 4 + r) * 16 + c16] = (__bf16)hn;
                        if (layer == 1 && k == TSEQ) {
                            const int b = (mtp * 2 + m) * 16 + q * 4 + r;
                            __hip_atomic_store(&h2p[b * HID + hidx], hn,
                                               __ATOMIC_RELAXED, __HIP_MEMORY_SCOPE_AGENT);
                        }
                    }
                }
                // overwrite + preload guard: all 32 prog >= max(1, k-1).
                // pf was issued at phase 1; drain + fence before first use.
                asm volatile("s_waitcnt vmcnt(0)" ::: "memory");
                __builtin_amdgcn_sched_barrier(0);
                {
                    int need = k - 1; if (need < 1) need = 1;
                    bool pok = (lane < 32) ? ((int)pf >= need) : true;
                    while (!__all(pok)) {
                        __builtin_amdgcn_s_sleep(1);
                        if (lane < 32) pf = load_flag_coh(flg + lane);
                        pok = (lane < 32) ? ((int)pf >= need) : true;
                    }
                }
                // wave-local LDS transpose -> 3 tagged 8B granule stores (fire&forget)
                char* hout = ws + (layer
                    ? OFF_RH2 + (size_t)((k + 3) & 3) * SLOT_SZ    // h2[k-1]: slot (k-1)&3
                    : OFF_RH1 + (size_t)(k & 3) * SLOT_SZ);        // h1[k]:   slot k&3
                const u64 tag48 = (u64)(unsigned)(layer ? k : k + 1) << 48;
                const int bt   = lane >> 5;
                const int qa1  = (lane >> 4) & 1;
                const int b15r = lane & 15;
                const u64* lp = (const u64*)&htr[half * 512 + (bt * 16 + b15r) * 16 + qa1 * 8];
                u64 v0 = lp[0], v1 = lp[1];
                const int f = (((mtp * 2 + bt) * 16) + bn) * 64 + (half * 2 + qa1) * 16 + b15r;
                char* gp = hout + (size_t)f * 24;
                st_gran(gp,      (v0 & 0xFFFFFFFFFFFFull) | tag48);
                st_gran(gp + 8,  ((v0 >> 48) | ((v1 & 0xFFFFFFFFull) << 16)) | tag48);
                st_gran(gp + 16, ((v1 >> 32) & 0xFFFFFFFFull) | tag48);
            }
        } else {
            // inactive round: still advance progress (peers' guards depend on it)
            if (threadIdx.x == 0)
                __hip_atomic_store(flg + layer * 16 + bn, (unsigned)(k + 2),
                                   __ATOMIC_RELAXED, __HIP_MEMORY_SCOPE_AGENT);
        }
    }

    // ---- final full handshake: h2p globally visible before FC ----
    asm volatile("s_waitcnt vmcnt(0)" ::: "memory");
    __syncthreads();
    if (threadIdx.x == 0)
        __hip_atomic_store(flg + layer * 16 + bn, (unsigned)(TSEQ + 3),
                           __ATOMIC_RELAXED, __HIP_MEMORY_SCOPE_AGENT);
    if (threadIdx.x < 32) {
        while ((int)load_flag_coh(flg + threadIdx.x) < TSEQ + 3)
            __builtin_amdgcn_s_sleep(1);
    }
    __syncthreads();

    // ---- fused FC epilogue: one batch per block (group-local mapping) ----
    if (threadIdx.x < 64) {
        const int b = mtp * 32 + layer * 16 + bn;
        const float* h = h2p + b * HID;
        float hv[8];
        #pragma unroll
        for (int j = 0; j < 8; ++j)
            hv[j] = __hip_atomic_load(&h[lane * 8 + j], __ATOMIC_RELAXED, __HIP_MEMORY_SCOPE_AGENT);
        float y[7];
        #pragma unroll
        for (int o = 0; o < 7; ++o) {
            const float* wrow = wfc + o * HID;
            float s = 0.f;
            #pragma unroll
            for (int j = 0; j < 8; ++j) s += hv[j] * wrow[lane * 8 + j];
            #pragma unroll
            for (int off = 32; off >= 1; off >>= 1) s += __shfl_down(s, off);
            y[o] = s;
        }
        if (lane == 0) {
            out[b * 3 + 0] = sigm(y[0] + bfc[0]);
            out[b * 3 + 1] = sigm(y[1] + bfc[1]);
            out[b * 3 + 2] = sigm(y[2] + bfc[2]);
            float r0 = tanh_fast(y[3] + bfc[3]);
            float r1 = tanh_fast(y[4] + bfc[4]);
            float r2 = tanh_fast(y[5] + bfc[5]);
            float r3 = tanh_fast(y[6] + bfc[6]);
            float n = sqrtf(r0 * r0 + r1 * r1 + r2 * r2 + r3 * r3);
            n = fmaxf(n, 1e-12f);
            out[768 + b * 4 + 0] = r0 / n;
            out[768 + b * 4 + 1] = r1 / n;
            out[768 + b * 4 + 2] = r2 / n;
            out[768 + b * 4 + 3] = r3 / n;
        }
    }
}

extern "C" void kernel_launch(void* const* d_in, const int* in_sizes, int n_in,
                              void* d_out, int out_size, void* d_ws, size_t ws_size,
                              hipStream_t stream)
{
    const float* x    = (const float*)d_in[0];
    const float* wih0 = (const float*)d_in[1];
    const float* whh0 = (const float*)d_in[2];
    const float* bih0 = (const float*)d_in[3];
    const float* bhh0 = (const float*)d_in[4];
    const float* wih1 = (const float*)d_in[5];
    const float* whh1 = (const float*)d_in[6];
    const float* bih1 = (const float*)d_in[7];
    const float* bhh1 = (const float*)d_in[8];
    const float* wfc  = (const float*)d_in[9];
    const float* bfc  = (const float*)d_in[10];
    char* ws = (char*)d_ws;

    // zero flags + h2p only; rings self-initialize via write-before-read tags
    hipMemsetAsync(ws + ZERO_OFF, 0, ZERO_LEN, stream);

    // prologue: pack weights into MFMA fragment order (bf16), combine biases.
    // (re-writing PW regions also re-garbages the overlaid rings each launch)
    pack_w<<<256,  256, 0, stream>>>(wih0, (__bf16*)(ws + OFF_PW_IH0), 0);
    pack_w<<<4096, 256, 0, stream>>>(whh0, (__bf16*)(ws + OFF_PW_HH0), 4);
    pack_w<<<4096, 256, 0, stream>>>(wih1, (__bf16*)(ws + OFF_PW_IH1), 4);
    pack_w<<<4096, 256, 0, stream>>>(whh1, (__bf16*)(ws + OFF_PW_HH1), 4);
    bias_comb<<<8, 256, 0, stream>>>(bih0, bhh0, bih1, bhh1,
                                     (float*)(ws + OFF_B0), (float*)(ws + OFF_B1));

    // one persistent kernel: weights register-resident, 201 pipelined steps
    lstm_persist<<<256, 256, 0, stream>>>(x, wfc, bfc, ws, (float*)d_out);
}

// Round 9
// 1954.609 us; speedup vs baseline: 2.7256x; 2.7256x over previous
//
#include <hip/hip_runtime.h>
#include <hip/hip_bf16.h>

#define TSEQ  200
#define BATCH 256
#define INDIM 32
#define HID   512
#define GATES 2048

typedef __bf16 bf16x8 __attribute__((ext_vector_type(8)));
typedef float  f32x4  __attribute__((ext_vector_type(4)));
typedef unsigned long long u64;

// ---- workspace layout (bytes) ----  (ends 0x825000, under the r5-proven 0x826000)
static constexpr size_t OFF_PW_IH0 = 0;          // 128 KB
static constexpr size_t OFF_PW_HH0 = 0x20000;    // 2 MB
static constexpr size_t OFF_PW_IH1 = 0x220000;   // 2 MB
static constexpr size_t OFF_PW_HH1 = 0x420000;   // 2 MB
static constexpr size_t OFF_B0     = 0x620000;   // 8 KB
static constexpr size_t OFF_B1     = 0x622000;   // 8 KB
static constexpr size_t OFF_H1     = 0x624000;   // h1 ring: 4 slots x 256 KB
static constexpr size_t OFF_H2     = 0x724000;   // h2 ring: 4 slots x 256 KB (was 2)
static constexpr size_t OFF_CTR    = 0x824000;   // 8 groups x 512 B: cflg[32] @+0, pflg[32] @+256
static constexpr size_t ZERO_OFF   = OFF_H1;
static constexpr size_t ZERO_LEN   = 0x825000 - OFF_H1;

__device__ __forceinline__ float sigm(float v) { return 1.f / (1.f + __expf(-v)); }

// guarded fast tanh: e = exp(-2|v|) in (0,1]; tanh(|v|) = (1-e)/(1+e); restore sign.
__device__ __forceinline__ float tanh_fast(float v) {
    float e = __expf(-2.0f * fabsf(v));
    float t = (1.0f - e) / (1.0f + e);
    return copysignf(t, v);
}

__device__ __forceinline__ bf16x8 as_bf16x8(f32x4 v) {
    union { f32x4 f; bf16x8 b; } u; u.f = v; return u.b;
}

// Coherent 16B fragment load (MALL), coalesces at TA/TCC. NOT waitcnt-tracked:
// callers MUST fence with s_waitcnt vmcnt(0) + sched_barrier(0) (rule 18).
__device__ __forceinline__ bf16x8 load16_coh(const bf16x8* p) {
    bf16x8 v;
    asm volatile("global_load_dwordx4 %0, %1, off sc0 sc1"
                 : "=v"(v) : "v"(p) : "memory");
    return v;
}

// Coherent 16B store (write-through to MALL).
__device__ __forceinline__ void store16_coh(void* p, u64 v0, u64 v1) {
    union { u64 u[2]; f32x4 f; } cv; cv.u[0] = v0; cv.u[1] = v1;
    asm volatile("global_store_dwordx4 %0, %1, off sc0 sc1"
                 :: "v"(p), "v"(cv.f) : "memory");
}

// Self-fencing coherent flag load (poll paths).
__device__ __forceinline__ unsigned load_flag_coh(const unsigned* p) {
    unsigned v;
    asm volatile("global_load_dword %0, %1, off sc0 sc1\n\t"
                 "s_waitcnt vmcnt(0)"
                 : "=v"(v) : "v"(p) : "memory");
    return v;
}

// Untracked coherent flag load (pre-issued; consume after a later manual drain).
__device__ __forceinline__ unsigned load_flag_async(const unsigned* p) {
    unsigned v;
    asm volatile("global_load_dword %0, %1, off sc0 sc1"
                 : "=v"(v) : "v"(p) : "memory");
    return v;
}

__device__ __forceinline__ void post_flag(unsigned* p, unsigned v) {
    __hip_atomic_store(p, v, __ATOMIC_RELAXED, __HIP_MEMORY_SCOPE_AGENT);
}

// Pack weight matrix W[2048][K] (fp32, row-major) into MFMA B-fragment order (bf16).
__global__ void pack_w(const float* __restrict__ W, __bf16* __restrict__ out, int ktlog2)
{
    int tid = blockIdx.x * 256 + threadIdx.x;
    int K = 32 << ktlog2;
    int j    = tid & 7;
    int lane = (tid >> 3) & 63;
    int rest = tid >> 9;
    int kt   = rest & ((1 << ktlog2) - 1);
    int r2   = rest >> ktlog2;
    int lnt  = r2 & 7;
    int bn   = r2 >> 3;
    int type = lnt >> 1, half = lnt & 1;
    int g    = type * 512 + bn * 32 + half * 16 + (lane & 15);
    int kcol = kt * 32 + (lane >> 4) * 8 + j;
    out[tid] = (__bf16)W[g * K + kcol];
}

__global__ void bias_comb(const float* __restrict__ a0, const float* __restrict__ a1,
                          const float* __restrict__ a2, const float* __restrict__ a3,
                          float* __restrict__ o0, float* __restrict__ o1)
{
    int tid = blockIdx.x * 256 + threadIdx.x;
    if (tid < GATES) { o0[tid] = a0[tid] + a1[tid]; o1[tid] = a2[tid] + a3[tid]; }
}

// Persistent pipelined 2-layer LSTM, weights register-resident.
// Grid: 256 blocks x 256 threads (4 waves). Blocks 0..127 layer0, 128..255 layer1.
// vs round 5 (verified 1433 us): the 32-block per-step LOCKSTEP barrier is
// REMOVED. Each wave now waits only on its true data dependencies:
//   L0 waves @k:     16 L0 pflags >= k   (h1[k-1])
//   L1 kh0 wave @k:  16 L0 pflags >= k   (h1[k-1])
//   L1 kh1 wave @k:  16 L1 pflags >= k   (h2[k-1]; skipped for k<2, zero state)
// pflag = k+1 posted per block after its step-k h store is DRAINED (S3).
// cflag = k+1 posted per block after its step-k staging (S1) -- consumed by
// writers as ring-overwrite guards (4-deep rings => need cflags >= k-2,
// 3 steps of slack, checked from a flag line PRE-ISSUED at S1, off-path).
// h2 ring deepened 2 -> 4; h2p dropped (FC reads the final ring slot, bf16).
__global__ __launch_bounds__(256, 1) void lstm_persist(const float* __restrict__ x,
                                                       const float* __restrict__ wfc,
                                                       const float* __restrict__ bfc,
                                                       char* __restrict__ ws,
                                                       float* __restrict__ out)
{
    const int layer = blockIdx.x >> 7;
    const int lb    = blockIdx.x & 127;
    const int mtp   = lb >> 4;            // batch group: [mtp*32, +32)
    const int bn    = lb & 15;            // hidden tile: [bn*32, +32)
    const int wid   = threadIdx.x >> 6;
    const int half  = wid & 1;
    const int kh    = wid >> 1;
    const int lane  = threadIdx.x & 63;
    const int q     = lane >> 4;
    const int c16   = lane & 15;
    unsigned* cflg  = (unsigned*)(ws + OFF_CTR) + (size_t)mtp * 128;  // consumer progress
    unsigned* pflg  = cflg + 64;                                      // producer data-ready

    __shared__ float  red[2][64][33];     // padded: conflict-free cross-wave reduction
    __shared__ __bf16 htr[1024];          // h transpose staging (kh0 waves only)
    __shared__ bf16x8 stg[2][2][16][64];  // A-frag dedup staging [kh][m][kt][lane], 64 KB

    const float* bias = (const float*)(ws + (layer ? OFF_B1 : OFF_B0));
    const int hidx = bn * 32 + half * 16 + c16;     // C/D col = lane&15
    const float bi  = bias[hidx];
    const float bff = bias[512 + hidx];
    const float bg  = bias[1024 + hidx];
    const float bo  = bias[1536 + hidx];

    const bf16x8* __restrict__ pBx = (const bf16x8*)(ws + OFF_PW_IH0);
    const bf16x8* __restrict__ pBh = (const bf16x8*)(ws + OFF_PW_HH0);
    const bf16x8* __restrict__ pB1 = (const bf16x8*)(ws + OFF_PW_IH1);
    const bf16x8* __restrict__ pB2 = (const bf16x8*)(ws + OFF_PW_HH1);

    // ---- preload weight slice into registers (once; written by prior dispatch) ----
    f32x4 Bw[64];                         // layer1: [kt(16)][ty(4)]; layer0: [kt(8)][ty(4)]
    f32x4 Bx[4];                          // layer0 x-projection frags
    if (layer == 0) {
        #pragma unroll
        for (int j = 0; j < 8; ++j)
            #pragma unroll
            for (int ty = 0; ty < 4; ++ty)
                Bw[j * 4 + ty] = *(const f32x4*)&pBh[((bn * 8 + ty * 2 + half) * 16 + kh * 8 + j) * 64 + lane];
        #pragma unroll
        for (int ty = 0; ty < 4; ++ty)
            Bx[ty] = *(const f32x4*)&pBx[(bn * 8 + ty * 2 + half) * 64 + lane];
    } else {
        const bf16x8* __restrict__ pW = kh ? pB2 : pB1;
        #pragma unroll
        for (int j = 0; j < 16; ++j)
            #pragma unroll
            for (int ty = 0; ty < 4; ++ty)
                Bw[j * 4 + ty] = *(const f32x4*)&pW[((bn * 8 + ty * 2 + half) * 16 + j) * 64 + lane];
    }

    float creg[8] = {0.f,0.f,0.f,0.f,0.f,0.f,0.f,0.f};   // c state (kh0 waves)

    // per-wave poll on 16 producer flags (lanes 0..15), coalesced single-line
    auto wait_flags16 = [&](const unsigned* base, int need) {
        bool ok = (lane < 16) ? ((int)load_flag_coh(base + lane) >= need) : true;
        while (!__all(ok)) {
            __builtin_amdgcn_s_sleep(1);
            ok = (lane < 16) ? ((int)load_flag_coh(base + lane) >= need) : true;
        }
    };

    for (int k = 0; k <= TSEQ; ++k) {
        const bool active = layer ? (k >= 1) : (k < TSEQ);
        if (active) {
            const int t = k - layer;
            f32x4 acc[2][4] = {};
            const size_t h1rd = OFF_H1 + (size_t)((k + 3) & 3) * 0x40000; // h1[k-1]

            // issue x loads before any waiting (independent of flags)
            float4 xlo[2], xhi[2];
            if (layer == 0 && kh == 0) {
                #pragma unroll
                for (int m = 0; m < 2; ++m) {
                    const int b = (mtp * 2 + m) * 16 + c16;
                    const float* xp = x + ((size_t)b * TSEQ + t) * INDIM + q * 8;
                    xlo[m] = *(const float4*)xp;
                    xhi[m] = *(const float4*)(xp + 4);
                }
            }

            // ---- phase 0: data-ready waits (per wave, only true deps) ----
            if (layer == 0) {
                if (k >= 1) wait_flags16(pflg, k);          // peers' h1[k-1]
            } else {
                if (kh == 0) wait_flags16(pflg, k);         // L0's h1[k-1]
                else if (k >= 2) wait_flags16(pflg + 16, k);// peers' h2[k-1]
            }

            // ---- phase 1: dedup staging (each wave loads its half's m-tile) ----
            if (layer == 0) {
                const bf16x8* __restrict__ pA = (const bf16x8*)(ws + h1rd);
                bf16x8 tmp0[8];
                #pragma unroll
                for (int j = 0; j < 8; ++j)
                    tmp0[j] = load16_coh(&pA[((mtp * 2 + half) * 16 + kh * 8 + j) * 64 + lane]);
                asm volatile("s_waitcnt vmcnt(0)" ::: "memory");
                __builtin_amdgcn_sched_barrier(0);
                #pragma unroll
                for (int j = 0; j < 8; ++j)
                    stg[kh][half][j][lane] = tmp0[j];
            } else {
                const bf16x8* __restrict__ pA = kh
                    ? (const bf16x8*)(ws + OFF_H2 + (size_t)((k + 3) & 3) * 0x40000) // h2[k-1]
                    : (const bf16x8*)(ws + h1rd);
                bf16x8 tmp[16];
                #pragma unroll
                for (int j = 0; j < 16; ++j)
                    tmp[j] = load16_coh(&pA[((mtp * 2 + half) * 16 + j) * 64 + lane]);
                asm volatile("s_waitcnt vmcnt(0)" ::: "memory");
                __builtin_amdgcn_sched_barrier(0);
                #pragma unroll
                for (int j = 0; j < 16; ++j)
                    stg[kh][half][j][lane] = tmp[j];
            }
            bf16x8 ax[2];
            if (layer == 0 && kh == 0) {
                #pragma unroll
                for (int m = 0; m < 2; ++m) {
                    ax[m][0] = (__bf16)xlo[m].x; ax[m][1] = (__bf16)xlo[m].y;
                    ax[m][2] = (__bf16)xlo[m].z; ax[m][3] = (__bf16)xlo[m].w;
                    ax[m][4] = (__bf16)xhi[m].x; ax[m][5] = (__bf16)xhi[m].y;
                    ax[m][6] = (__bf16)xhi[m].z; ax[m][7] = (__bf16)xhi[m].w;
                }
            }
            __syncthreads();                                 // S1: staging complete
            if (threadIdx.x == 0)
                post_flag(cflg + layer * 16 + bn, (unsigned)(k + 1));  // staged step k
            unsigned pf = 0;
            if (kh == 0 && lane < 32) pf = load_flag_async(cflg + lane); // pre-issue guard

            // ---- phase 2: LDS -> registers ----
            bf16x8 a0[16], a1[16];
            if (layer == 0) {
                #pragma unroll
                for (int j = 0; j < 8; ++j) {
                    a0[j]     = stg[kh][0][j][lane];
                    a0[8 + j] = stg[kh][1][j][lane];
                }
            } else {
                #pragma unroll
                for (int j = 0; j < 8; ++j) {
                    a0[j]     = stg[kh][0][j][lane];
                    a0[8 + j] = stg[kh][1][j][lane];
                    a1[j]     = stg[kh][0][8 + j][lane];
                    a1[8 + j] = stg[kh][1][8 + j][lane];
                }
            }
            __syncthreads();                                 // S_read: stg reuse guard

            // ---- phase 3: MFMAs ----
            if (layer == 0) {
                if (kh == 0) {
                    #pragma unroll
                    for (int m = 0; m < 2; ++m)
                        #pragma unroll
                        for (int ty = 0; ty < 4; ++ty)
                            acc[m][ty] = __builtin_amdgcn_mfma_f32_16x16x32_bf16(ax[m], as_bf16x8(Bx[ty]), acc[m][ty], 0, 0, 0);
                }
                #pragma unroll
                for (int j = 0; j < 8; ++j) {
                    #pragma unroll
                    for (int ty = 0; ty < 4; ++ty) {
                        acc[0][ty] = __builtin_amdgcn_mfma_f32_16x16x32_bf16(a0[j],     as_bf16x8(Bw[j * 4 + ty]), acc[0][ty], 0, 0, 0);
                        acc[1][ty] = __builtin_amdgcn_mfma_f32_16x16x32_bf16(a0[8 + j], as_bf16x8(Bw[j * 4 + ty]), acc[1][ty], 0, 0, 0);
                    }
                }
            } else {
                #pragma unroll
                for (int j = 0; j < 8; ++j) {
                    #pragma unroll
                    for (int ty = 0; ty < 4; ++ty) {
                        acc[0][ty] = __builtin_amdgcn_mfma_f32_16x16x32_bf16(a0[j],     as_bf16x8(Bw[j * 4 + ty]), acc[0][ty], 0, 0, 0);
                        acc[1][ty] = __builtin_amdgcn_mfma_f32_16x16x32_bf16(a0[8 + j], as_bf16x8(Bw[j * 4 + ty]), acc[1][ty], 0, 0, 0);
                    }
                }
                #pragma unroll
                for (int j = 0; j < 8; ++j) {
                    #pragma unroll
                    for (int ty = 0; ty < 4; ++ty) {
                        acc[0][ty] = __builtin_amdgcn_mfma_f32_16x16x32_bf16(a1[j],     as_bf16x8(Bw[(8 + j) * 4 + ty]), acc[0][ty], 0, 0, 0);
                        acc[1][ty] = __builtin_amdgcn_mfma_f32_16x16x32_bf16(a1[8 + j], as_bf16x8(Bw[(8 + j) * 4 + ty]), acc[1][ty], 0, 0, 0);
                    }
                }
            }

            // ---- phase 4: cross-wave K reduction ----
            if (kh == 1) {
                #pragma unroll
                for (int m = 0; m < 2; ++m)
                    #pragma unroll
                    for (int ty = 0; ty < 4; ++ty)
                        #pragma unroll
                        for (int r = 0; r < 4; ++r)
                            red[half][lane][m * 16 + ty * 4 + r] = acc[m][ty][r];
            }
            __syncthreads();                                 // S2: reduction ready

            // ---- phase 5 (kh0): activation + ring store ----
            if (kh == 0) {
                #pragma unroll
                for (int m = 0; m < 2; ++m) {
                    #pragma unroll
                    for (int r = 0; r < 4; ++r) {
                        float pi  = acc[m][0][r] + red[half][lane][m * 16 + r]      + bi;
                        float pff = acc[m][1][r] + red[half][lane][m * 16 + 4 + r]  + bff;
                        float pg  = acc[m][2][r] + red[half][lane][m * 16 + 8 + r]  + bg;
                        float po  = acc[m][3][r] + red[half][lane][m * 16 + 12 + r] + bo;
                        float cn = sigm(pff) * creg[m * 4 + r] + sigm(pi) * tanh_fast(pg);
                        float hn = sigm(po) * tanh_fast(cn);
                        creg[m * 4 + r] = cn;
                        htr[half * 512 + (m * 16 + q * 4 + r) * 16 + c16] = (__bf16)hn;
                    }
                }
                // ring-overwrite guard: consumers staged >= k-3 (cflag >= k-2).
                // pf pre-issued at S1; drain + fence before first use (rule 18).
                asm volatile("s_waitcnt vmcnt(0)" ::: "memory");
                __builtin_amdgcn_sched_barrier(0);
                {
                    const int need = k - 2;
                    bool pok = (lane < 32)
                        ? ((layer == 1 && lane < 16) ? true : ((int)pf >= need))
                        : true;
                    while (!__all(pok)) {
                        __builtin_amdgcn_s_sleep(1);
                        if (lane < 32) pf = load_flag_coh(cflg + lane);
                        pok = (lane < 32)
                            ? ((layer == 1 && lane < 16) ? true : ((int)pf >= need))
                            : true;
                    }
                }
                // wave-local LDS transpose -> one coalesced 16B coherent store
                __bf16* __restrict__ hout = (__bf16*)(ws + (layer
                    ? OFF_H2 + (size_t)(k & 3) * 0x40000
                    : OFF_H1 + (size_t)(k & 3) * 0x40000));
                const int bt   = lane >> 5;
                const int qa1  = (lane >> 4) & 1;
                const int b15r = lane & 15;
                const u64* lp = (const u64*)&htr[half * 512 + (bt * 16 + b15r) * 16 + qa1 * 8];
                u64 v0 = lp[0], v1 = lp[1];
                const int f = (((mtp * 2 + bt) * 16) + bn) * 64 + (half * 2 + qa1) * 16 + b15r;
                u64* gp = (u64*)hout + (size_t)f * 2;
                store16_coh(gp, v0, v1);
                asm volatile("s_waitcnt vmcnt(0)" ::: "memory");   // drain before pflag
            }
            __syncthreads();                                 // S3: stores drained block-wide
            if (threadIdx.x == 0)
                post_flag(pflg + layer * 16 + bn, (unsigned)(k + 1));  // h[k] ready
        } else {
            if (threadIdx.x == 0) {
                post_flag(cflg + layer * 16 + bn, (unsigned)(k + 1));
                post_flag(pflg + layer * 16 + bn, (unsigned)(k + 1));
            }
        }
    }

    // ---- FC epilogue: wait for all L1 final stores, read h2 from ring (bf16) ----
    if (threadIdx.x < 64) {
        {
            bool ok = (lane < 16) ? ((int)load_flag_coh(pflg + 16 + lane) >= TSEQ + 1) : true;
            while (!__all(ok)) {
                __builtin_amdgcn_s_sleep(1);
                ok = (lane < 16) ? ((int)load_flag_coh(pflg + 16 + lane) >= TSEQ + 1) : true;
            }
        }
        const int b = mtp * 32 + layer * 16 + bn;
        const bf16x8* ring = (const bf16x8*)(ws + OFF_H2 + (size_t)(TSEQ & 3) * 0x40000);
        // A-frag layout: frag a holds batch (a/64/16)*16 + (lane&15) at hcols kt*32+q*8+j
        const int a = ((b >> 4) * 16 + (lane >> 2)) * 64 + ((lane & 3) << 4) + (b & 15);
        bf16x8 hb = load16_coh(ring + a);
        asm volatile("s_waitcnt vmcnt(0)" ::: "memory");
        __builtin_amdgcn_sched_barrier(0);
        float hv[8];
        #pragma unroll
        for (int j = 0; j < 8; ++j) hv[j] = (float)hb[j];
        float y[7];
        #pragma unroll
        for (int o = 0; o < 7; ++o) {
            const float* wrow = wfc + o * HID;
            float s = 0.f;
            #pragma unroll
            for (int j = 0; j < 8; ++j) s += hv[j] * wrow[lane * 8 + j];
            #pragma unroll
            for (int off = 32; off >= 1; off >>= 1) s += __shfl_down(s, off);
            y[o] = s;
        }
        if (lane == 0) {
            out[b * 3 + 0] = sigm(y[0] + bfc[0]);
            out[b * 3 + 1] = sigm(y[1] + bfc[1]);
            out[b * 3 + 2] = sigm(y[2] + bfc[2]);
            float r0 = tanh_fast(y[3] + bfc[3]);
            float r1 = tanh_fast(y[4] + bfc[4]);
            float r2 = tanh_fast(y[5] + bfc[5]);
            float r3 = tanh_fast(y[6] + bfc[6]);
            float n = sqrtf(r0 * r0 + r1 * r1 + r2 * r2 + r3 * r3);
            n = fmaxf(n, 1e-12f);
            out[768 + b * 4 + 0] = r0 / n;
            out[768 + b * 4 + 1] = r1 / n;
            out[768 + b * 4 + 2] = r2 / n;
            out[768 + b * 4 + 3] = r3 / n;
        }
    }
}

extern "C" void kernel_launch(void* const* d_in, const int* in_sizes, int n_in,
                              void* d_out, int out_size, void* d_ws, size_t ws_size,
                              hipStream_t stream)
{
    const float* x    = (const float*)d_in[0];
    const float* wih0 = (const float*)d_in[1];
    const float* whh0 = (const float*)d_in[2];
    const float* bih0 = (const float*)d_in[3];
    const float* bhh0 = (const float*)d_in[4];
    const float* wih1 = (const float*)d_in[5];
    const float* whh1 = (const float*)d_in[6];
    const float* bih1 = (const float*)d_in[7];
    const float* bhh1 = (const float*)d_in[8];
    const float* wfc  = (const float*)d_in[9];
    const float* bfc  = (const float*)d_in[10];
    char* ws = (char*)d_ws;

    // zero h rings + flags
    hipMemsetAsync(ws + ZERO_OFF, 0, ZERO_LEN, stream);

    // prologue: pack weights into MFMA fragment order (bf16), combine biases
    pack_w<<<256,  256, 0, stream>>>(wih0, (__bf16*)(ws + OFF_PW_IH0), 0);
    pack_w<<<4096, 256, 0, stream>>>(whh0, (__bf16*)(ws + OFF_PW_HH0), 4);
    pack_w<<<4096, 256, 0, stream>>>(wih1, (__bf16*)(ws + OFF_PW_IH1), 4);
    pack_w<<<4096, 256, 0, stream>>>(whh1, (__bf16*)(ws + OFF_PW_HH1), 4);
    bias_comb<<<8, 256, 0, stream>>>(bih0, bhh0, bih1, bhh1,
                                     (float*)(ws + OFF_B0), (float*)(ws + OFF_B1));

    // one persistent kernel: weights register-resident, 201 pipelined steps
    lstm_persist<<<256, 256, 0, stream>>>(x, wfc, bfc, ws, (float*)d_out);
}